// Round 1
// baseline (5112.016 us; speedup 1.0000x reference)
//
#include <hip/hip_runtime.h>
#include <math.h>

// LSTM_1829656068756: BN(channels=T) -> LSTM(1->64) -> LSTM(64->64) -> FC(64)+GELU
// B=262144, T=15, IN=1, H=64. fp32 everywhere (v1 correctness baseline).
//
// ws layout (floats):
//   [0..30)      scale[15], shift[15]        (BN folded to x*scale+shift)
//   [32..288)    b0 = b_ih0+b_hh0  [256]
//   [288..544)   b1 = b_ih1+b_hh1  [256]
//   [1024..)     wT_hh0  [64][256]   (wT[k][j] = w[j][k])
//   [17408..)    wT_1cat [128][256]  (rows 0..63 = w_ih1^T, 64..127 = w_hh1^T)
//   [50176..)    fcT     [64][64]
// total 54272 floats = 217 KB of d_ws.

namespace {
constexpr int kB = 262144;
constexpr int kT = 15;

constexpr int WS_SS = 0;
constexpr int WS_B0 = 32;
constexpr int WS_B1 = 288;
constexpr int WS_WHH0T = 1024;
constexpr int WS_W1T = 17408;
constexpr int WS_FCT = 50176;
}  // namespace

__device__ __forceinline__ float fast_sigmoid(float x) {
  return __builtin_amdgcn_rcpf(1.f + __expf(-x));
}
__device__ __forceinline__ float fast_tanh(float x) {
  // tanh(x) = 1 - 2/(1+e^{2x}); saturates correctly for |x| large (e^inf -> rcp=0)
  return 1.f - 2.f * __builtin_amdgcn_rcpf(1.f + __expf(2.f * x));
}

__global__ void prep_kernel(const float* __restrict__ w_hh0,
                            const float* __restrict__ w_ih1,
                            const float* __restrict__ w_hh1,
                            const float* __restrict__ b_ih0,
                            const float* __restrict__ b_hh0,
                            const float* __restrict__ b_ih1,
                            const float* __restrict__ b_hh1,
                            const float* __restrict__ fc_w,
                            float* __restrict__ ws) {
  const int stride = gridDim.x * blockDim.x;
  const int t0 = blockIdx.x * blockDim.x + threadIdx.x;
  for (int i = t0; i < 64 * 256; i += stride) {
    int k = i >> 8, j = i & 255;
    ws[WS_WHH0T + i] = w_hh0[j * 64 + k];
  }
  for (int i = t0; i < 128 * 256; i += stride) {
    int k = i >> 8, j = i & 255;
    ws[WS_W1T + i] = (k < 64) ? w_ih1[j * 64 + k] : w_hh1[j * 64 + k - 64];
  }
  for (int i = t0; i < 64 * 64; i += stride) {
    int k = i >> 6, o = i & 63;
    ws[WS_FCT + i] = fc_w[o * 64 + k];
  }
  for (int i = t0; i < 256; i += stride) {
    ws[WS_B0 + i] = b_ih0[i] + b_hh0[i];
    ws[WS_B1 + i] = b_ih1[i] + b_hh1[i];
  }
}

__global__ void bn_stats_kernel(const float* __restrict__ x,
                                const float* __restrict__ gamma,
                                const float* __restrict__ beta,
                                float* __restrict__ ws) {
  const int t = blockIdx.x;   // 0..14 (channel = timestep)
  const int tid = threadIdx.x;
  float s = 0.f, sq = 0.f;
  for (int j = tid; j < kB; j += 256) {
    float v = x[(size_t)j * kT + t];
    s += v;
    sq += v * v;
  }
  __shared__ float ls[256], lq[256];
  ls[tid] = s;
  lq[tid] = sq;
  __syncthreads();
  for (int off = 128; off > 0; off >>= 1) {
    if (tid < off) {
      ls[tid] += ls[tid + off];
      lq[tid] += lq[tid + off];
    }
    __syncthreads();
  }
  if (tid == 0) {
    const float inv_n = 1.f / (float)kB;
    float mean = ls[0] * inv_n;
    float var = lq[0] * inv_n - mean * mean;   // biased var (training-mode BN)
    float sc = gamma[t] * rsqrtf(var + 1e-5f);
    ws[WS_SS + t] = sc;
    ws[WS_SS + 15 + t] = beta[t] - mean * sc;
  }
}

// Fused BN-apply + LSTM0 + LSTM1 + FC + GELU.
// Block: 256 threads, M=32 batch rows. Thread (tr=tid>>6, tc=tid&63):
//   matmul phase: output tile rows tr*8..+7, cols tc*4..+3 (acc[8][4], outer product)
//   gate/fc phase: h-column tc, rows tr*8..+7 (c-state in registers)
// LDS: z[32][260] (padded), hcat[128][36] = transposed [h0;h1] state, xs[32][16].
__global__ __launch_bounds__(256) void lstm_fused_kernel(
    const float* __restrict__ x, const float* __restrict__ w_ih0,
    const float* __restrict__ fc_b, const float* __restrict__ ws,
    float* __restrict__ out) {
  __shared__ float z[32 * 260];
  __shared__ float hcat[128 * 36];   // hcat[k][m]: k<64 -> h0[k], k>=64 -> h1[k-64]
  __shared__ float xs[32 * 16];

  const int tid = threadIdx.x;
  const int bm0 = blockIdx.x * 32;
  const int tr = tid >> 6;
  const int tc = tid & 63;
  const int r0 = tr * 8;
  const int c0 = tc * 4;

  // stage x tile with BN folded in (480 contiguous floats, coalesced)
  for (int i = tid; i < 32 * kT; i += 256) {
    float v = x[(size_t)bm0 * kT + i];
    int m = i / 15, tt = i - m * 15;
    xs[m * 16 + tt] = v * ws[WS_SS + tt] + ws[WS_SS + 15 + tt];
  }
  for (int i = tid; i < 128 * 36; i += 256) hcat[i] = 0.f;

  float b0r[4], b1r[4], w0r[4];
#pragma unroll
  for (int j = 0; j < 4; ++j) {
    b0r[j] = ws[WS_B0 + c0 + j];
    b1r[j] = ws[WS_B1 + c0 + j];
    w0r[j] = w_ih0[c0 + j];
  }
  float c0r[8], c1r[8];
#pragma unroll
  for (int i = 0; i < 8; ++i) {
    c0r[i] = 0.f;
    c1r[i] = 0.f;
  }

  const float4* whh0T4 = reinterpret_cast<const float4*>(ws + WS_WHH0T);
  const float4* w1T4 = reinterpret_cast<const float4*>(ws + WS_W1T);

  __syncthreads();

  float acc[8][4];

  for (int t = 0; t < kT; ++t) {
    // ---------------- layer 0: z = b0 + x_t*w_ih0 + h0 @ w_hh0^T ----------------
#pragma unroll
    for (int i = 0; i < 8; ++i) {
      float xv = xs[(r0 + i) * 16 + t];
#pragma unroll
      for (int j = 0; j < 4; ++j) acc[i][j] = fmaf(xv, w0r[j], b0r[j]);
    }
#pragma unroll 4
    for (int k = 0; k < 64; ++k) {
      float4 w = whh0T4[k * 64 + tc];                                        // global, coalesced 1KB/wave
      float4 ha = *reinterpret_cast<const float4*>(&hcat[k * 36 + r0]);      // LDS broadcast
      float4 hb = *reinterpret_cast<const float4*>(&hcat[k * 36 + r0 + 4]);
      float hv[8] = {ha.x, ha.y, ha.z, ha.w, hb.x, hb.y, hb.z, hb.w};
      float wv[4] = {w.x, w.y, w.z, w.w};
#pragma unroll
      for (int i = 0; i < 8; ++i)
#pragma unroll
        for (int j = 0; j < 4; ++j) acc[i][j] = fmaf(hv[i], wv[j], acc[i][j]);
    }
#pragma unroll
    for (int i = 0; i < 8; ++i)
      *reinterpret_cast<float4*>(&z[(r0 + i) * 260 + c0]) =
          make_float4(acc[i][0], acc[i][1], acc[i][2], acc[i][3]);
    __syncthreads();

    // gates layer 0 (i,f,g,o), c in registers, write h0 transposed into hcat[0..64)
#pragma unroll
    for (int i = 0; i < 8; ++i) {
      const int m = r0 + i;
      float zi = z[m * 260 + tc];
      float zf = z[m * 260 + 64 + tc];
      float zg = z[m * 260 + 128 + tc];
      float zo = z[m * 260 + 192 + tc];
      float ig = fast_sigmoid(zi);
      float fg = fast_sigmoid(zf);
      float gg = fast_tanh(zg);
      float og = fast_sigmoid(zo);
      float c = fmaf(fg, c0r[i], ig * gg);
      c0r[i] = c;
      hcat[tc * 36 + m] = og * fast_tanh(c);
    }
    __syncthreads();

    // ---------------- layer 1: z = b1 + [h0_new; h1] @ [w_ih1; w_hh1]^T ----------------
#pragma unroll
    for (int i = 0; i < 8; ++i)
#pragma unroll
      for (int j = 0; j < 4; ++j) acc[i][j] = b1r[j];
#pragma unroll 4
    for (int k = 0; k < 128; ++k) {
      float4 w = w1T4[k * 64 + tc];
      float4 ha = *reinterpret_cast<const float4*>(&hcat[k * 36 + r0]);
      float4 hb = *reinterpret_cast<const float4*>(&hcat[k * 36 + r0 + 4]);
      float hv[8] = {ha.x, ha.y, ha.z, ha.w, hb.x, hb.y, hb.z, hb.w};
      float wv[4] = {w.x, w.y, w.z, w.w};
#pragma unroll
      for (int i = 0; i < 8; ++i)
#pragma unroll
        for (int j = 0; j < 4; ++j) acc[i][j] = fmaf(hv[i], wv[j], acc[i][j]);
    }
#pragma unroll
    for (int i = 0; i < 8; ++i)
      *reinterpret_cast<float4*>(&z[(r0 + i) * 260 + c0]) =
          make_float4(acc[i][0], acc[i][1], acc[i][2], acc[i][3]);
    __syncthreads();

    // gates layer 1, write h1 into hcat[64..128)
#pragma unroll
    for (int i = 0; i < 8; ++i) {
      const int m = r0 + i;
      float zi = z[m * 260 + tc];
      float zf = z[m * 260 + 64 + tc];
      float zg = z[m * 260 + 128 + tc];
      float zo = z[m * 260 + 192 + tc];
      float ig = fast_sigmoid(zi);
      float fg = fast_sigmoid(zf);
      float gg = fast_tanh(zg);
      float og = fast_sigmoid(zo);
      float c = fmaf(fg, c1r[i], ig * gg);
      c1r[i] = c;
      hcat[(64 + tc) * 36 + m] = og * fast_tanh(c);
    }
    __syncthreads();
  }

  // ---------------- FC + exact-erf GELU on h1 ----------------
  float yacc[8];
#pragma unroll
  for (int i = 0; i < 8; ++i) yacc[i] = fc_b[tc];
#pragma unroll 4
  for (int k = 0; k < 64; ++k) {
    float w = ws[WS_FCT + k * 64 + tc];
#pragma unroll
    for (int i = 0; i < 8; ++i)
      yacc[i] = fmaf(hcat[(64 + k) * 36 + r0 + i], w, yacc[i]);
  }
#pragma unroll
  for (int i = 0; i < 8; ++i) {
    float v = yacc[i];
    float g = 0.5f * v * (1.f + erff(v * 0.70710678118654752f));
    out[(size_t)(bm0 + r0 + i) * 64 + tc] = g;
  }
}

extern "C" void kernel_launch(void* const* d_in, const int* in_sizes, int n_in,
                              void* d_out, int out_size, void* d_ws, size_t ws_size,
                              hipStream_t stream) {
  const float* x = (const float*)d_in[0];
  const float* bn_gamma = (const float*)d_in[1];
  const float* bn_beta = (const float*)d_in[2];
  const float* w_ih0 = (const float*)d_in[3];
  const float* w_hh0 = (const float*)d_in[4];
  const float* b_ih0 = (const float*)d_in[5];
  const float* b_hh0 = (const float*)d_in[6];
  const float* w_ih1 = (const float*)d_in[7];
  const float* w_hh1 = (const float*)d_in[8];
  const float* b_ih1 = (const float*)d_in[9];
  const float* b_hh1 = (const float*)d_in[10];
  const float* fc_w = (const float*)d_in[11];
  const float* fc_b = (const float*)d_in[12];
  float* ws = (float*)d_ws;
  float* out = (float*)d_out;

  hipLaunchKernelGGL(prep_kernel, dim3(64), dim3(256), 0, stream,
                     w_hh0, w_ih1, w_hh1, b_ih0, b_hh0, b_ih1, b_hh1, fc_w, ws);
  hipLaunchKernelGGL(bn_stats_kernel, dim3(15), dim3(256), 0, stream,
                     x, bn_gamma, bn_beta, ws);
  hipLaunchKernelGGL(lstm_fused_kernel, dim3(kB / 32), dim3(256), 0, stream,
                     x, w_ih0, fc_b, ws, out);
}

// Round 2
// 3509.077 us; speedup vs baseline: 1.4568x; 1.4568x over previous
//
#include <hip/hip_runtime.h>
#include <math.h>

// BN(ch=T) -> LSTM(1->64) -> LSTM(64->64) -> FC+GELU.  B=262144 T=15 H=64.
// v2: recurrent matmuls on bf16 MFMA (16x16x32), gates/c/x-term/FC in fp32.
//
// ws float offsets:
//   WS_SS    0     scale[15]@+0, shift[15]@+16
//   WS_B0    32    b_ih0+b_hh0 [256]
//   WS_B1    288   b_ih1+b_hh1 [256]
//   WS_FCT   1024  fcT[u][o] fp32 [64][64]
//   WS_STATS 5200  bn sums[15]@+0, sqsums[15]@+16
//   WS_BF    8192  bf16 B-fragments: 96 chunks x 64 lanes x 8 ushort (96 KB)
//     chunk<32:  L0 (w_hh0^T):  ks=chunk>>4 (K=64: 2), nt=chunk&15
//     chunk>=32: L1 ([w_ih1;w_hh1]^T): ks=(chunk-32)>>4 (K=128: 4), nt=&15
//     elem(lane,j) = B[k=32*ks+8*(lane>>4)+j][n=16*nt+(lane&15)]

typedef __attribute__((ext_vector_type(8))) short short8;
typedef __attribute__((ext_vector_type(4))) float f32x4;

namespace {
constexpr int kB = 262144;
constexpr int kT = 15;
constexpr int WS_SS = 0;
constexpr int WS_B0 = 32;
constexpr int WS_B1 = 288;
constexpr int WS_FCT = 1024;
constexpr int WS_STATS = 5200;
constexpr int WS_BF = 8192;
}  // namespace

__device__ __forceinline__ float sigm(float x) {
  return __builtin_amdgcn_rcpf(1.f + __expf(-x));
}
__device__ __forceinline__ float tanhx(float x) {
  return 1.f - 2.f * __builtin_amdgcn_rcpf(1.f + __expf(2.f * x));
}
__device__ __forceinline__ ushort f2bf(float f) {
  unsigned u = __float_as_uint(f);
  unsigned r = (u + 0x7fffu + ((u >> 16) & 1u)) >> 16;  // RNE
  return (ushort)r;
}

__global__ void prep_kernel(const float* __restrict__ w_hh0,
                            const float* __restrict__ w_ih1,
                            const float* __restrict__ w_hh1,
                            const float* __restrict__ b_ih0,
                            const float* __restrict__ b_hh0,
                            const float* __restrict__ b_ih1,
                            const float* __restrict__ b_hh1,
                            const float* __restrict__ fc_w,
                            float* __restrict__ ws) {
  const int stride = gridDim.x * blockDim.x;
  const int t0 = blockIdx.x * blockDim.x + threadIdx.x;
  ushort* bf = (ushort*)(ws + WS_BF);
  for (int i = t0; i < 96 * 512; i += stride) {
    int chunk = i >> 9, lane = (i >> 3) & 63, j = i & 7;
    float v;
    if (chunk < 32) {
      int ks = chunk >> 4, nt = chunk & 15;
      int k = 32 * ks + 8 * (lane >> 4) + j;
      int n = 16 * nt + (lane & 15);
      v = w_hh0[n * 64 + k];
    } else {
      int c2 = chunk - 32;
      int ks = c2 >> 4, nt = c2 & 15;
      int k = 32 * ks + 8 * (lane >> 4) + j;
      int n = 16 * nt + (lane & 15);
      v = (k < 64) ? w_ih1[n * 64 + k] : w_hh1[n * 64 + (k - 64)];
    }
    bf[i] = f2bf(v);
  }
  for (int i = t0; i < 4096; i += stride) {
    int u = i >> 6, o = i & 63;
    ws[WS_FCT + i] = fc_w[o * 64 + u];
  }
  for (int i = t0; i < 256; i += stride) {
    ws[WS_B0 + i] = b_ih0[i] + b_hh0[i];
    ws[WS_B1 + i] = b_ih1[i] + b_hh1[i];
  }
  for (int i = t0; i < 32; i += stride) ws[WS_STATS + i] = 0.f;
}

__global__ void bn_sums_kernel(const float* __restrict__ x,
                               float* __restrict__ ws) {
  __shared__ float ls[16], lq[16];
  const int tid = threadIdx.x;
  if (tid < 16) { ls[tid] = 0.f; lq[tid] = 0.f; }
  __syncthreads();
  const int N4 = kB * kT / 4;
  const float4* x4 = (const float4*)x;
  for (int i = blockIdx.x * blockDim.x + tid; i < N4; i += gridDim.x * blockDim.x) {
    float4 v = x4[i];
    int t = (4 * i) % 15;
    float vv[4] = {v.x, v.y, v.z, v.w};
#pragma unroll
    for (int j = 0; j < 4; ++j) {
      atomicAdd(&ls[t], vv[j]);
      atomicAdd(&lq[t], vv[j] * vv[j]);
      if (++t == 15) t = 0;
    }
  }
  __syncthreads();
  if (tid < 15) {
    atomicAdd(&ws[WS_STATS + tid], ls[tid]);
    atomicAdd(&ws[WS_STATS + 16 + tid], lq[tid]);
  }
}

__global__ void bn_final_kernel(const float* __restrict__ gamma,
                                const float* __restrict__ beta,
                                float* __restrict__ ws) {
  int t = threadIdx.x;
  if (t < 15) {
    const float inv = 1.f / (float)kB;
    float mean = ws[WS_STATS + t] * inv;
    float var = ws[WS_STATS + 16 + t] * inv - mean * mean;
    float sc = gamma[t] * rsqrtf(var + 1e-5f);
    ws[WS_SS + t] = sc;
    ws[WS_SS + 16 + t] = beta[t] - mean * sc;
  }
}

// smem layout (bytes): [0,8192) hcat ushort[32][128] (XOR-swizzled rows)
//                      [8192,10368) xs float[32][17]
//                      phase-2 alias: [0,8704) h1f float[32][68]
__global__ __launch_bounds__(256, 3) void lstm_fused_kernel(
    const float* __restrict__ x, const float* __restrict__ w_ih0,
    const float* __restrict__ fc_b, const float* __restrict__ ws,
    float* __restrict__ out) {
  __shared__ __align__(16) char smem[10368];
  ushort* hc = (ushort*)smem;
  float* xsf = (float*)(smem + 8192);

  const int tid = threadIdx.x;
  const int bm0 = blockIdx.x * 32;
  const int lane = tid & 63;
  const int wv = tid >> 6;
  const int grp = lane >> 4;
  const int l15 = lane & 15;
  const int u = wv * 16 + l15;

  // stage x with BN folded
  for (int i = tid; i < 32 * kT; i += 256) {
    float v = x[(size_t)bm0 * kT + i];
    int m = i / 15, tt = i - m * 15;
    xsf[m * 17 + tt] = v * ws[WS_SS + tt] + ws[WS_SS + 16 + tt];
  }
  for (int i = tid; i < 2048; i += 256) ((unsigned*)hc)[i] = 0u;

  float b0g[4], b1g[4], w0g[4];
#pragma unroll
  for (int j = 0; j < 4; ++j) {
    b0g[j] = ws[WS_B0 + u + 64 * j];
    b1g[j] = ws[WS_B1 + u + 64 * j];
    w0g[j] = w_ih0[u + 64 * j];
  }
  float c0r[8], c1r[8];
#pragma unroll
  for (int i = 0; i < 8; ++i) { c0r[i] = 0.f; c1r[i] = 0.f; }

  const short8* bfr = (const short8*)(ws + WS_BF);

  auto ldA = [&](int mt, int ks) -> short8 {
    int row = l15 + 16 * mt;
    int k0 = (32 * ks + 8 * grp) ^ ((row & 7) << 3);
    return *(const short8*)&hc[row * 128 + k0];
  };

  __syncthreads();

  for (int t = 0; t < kT; ++t) {
    // ---------------- layer 0: acc = b0 + x*w_ih0 + h0 @ w_hh0^T ----------------
    f32x4 acc[2][4];
#pragma unroll
    for (int mt = 0; mt < 2; ++mt)
#pragma unroll
      for (int r = 0; r < 4; ++r) {
        float xv = xsf[(16 * mt + 4 * grp + r) * 17 + t];
#pragma unroll
        for (int j = 0; j < 4; ++j) acc[mt][j][r] = fmaf(xv, w0g[j], b0g[j]);
      }
#pragma unroll
    for (int ks = 0; ks < 2; ++ks) {
      short8 a0 = ldA(0, ks);
      short8 a1 = ldA(1, ks);
#pragma unroll
      for (int j = 0; j < 4; ++j) {
        short8 bb = bfr[(ks * 16 + wv + 4 * j) * 64 + lane];
        acc[0][j] = __builtin_amdgcn_mfma_f32_16x16x32_bf16(a0, bb, acc[0][j], 0, 0, 0);
        acc[1][j] = __builtin_amdgcn_mfma_f32_16x16x32_bf16(a1, bb, acc[1][j], 0, 0, 0);
      }
    }
    __syncthreads();  // all A-reads done before h0 writes
    // gates L0 -> h0_t into hcat cols [0,64)
#pragma unroll
    for (int mt = 0; mt < 2; ++mt)
#pragma unroll
      for (int r = 0; r < 4; ++r) {
        int row = 16 * mt + 4 * grp + r;
        float zi = acc[mt][0][r], zf = acc[mt][1][r];
        float zg = acc[mt][2][r], zo = acc[mt][3][r];
        float ig = sigm(zi), fg = sigm(zf), gg = tanhx(zg), og = sigm(zo);
        float c = fmaf(fg, c0r[mt * 4 + r], ig * gg);
        c0r[mt * 4 + r] = c;
        float h = og * tanhx(c);
        hc[row * 128 + (u ^ ((row & 7) << 3))] = f2bf(h);
      }
    __syncthreads();  // h0_t visible

    // ---------------- layer 1: acc = b1 + [h0_t; h1_{t-1}] @ W1^T ----------------
#pragma unroll
    for (int mt = 0; mt < 2; ++mt)
#pragma unroll
      for (int j = 0; j < 4; ++j)
#pragma unroll
        for (int r = 0; r < 4; ++r) acc[mt][j][r] = b1g[j];
#pragma unroll
    for (int ks = 0; ks < 4; ++ks) {
      short8 a0 = ldA(0, ks);
      short8 a1 = ldA(1, ks);
#pragma unroll
      for (int j = 0; j < 4; ++j) {
        short8 bb = bfr[(32 + ks * 16 + wv + 4 * j) * 64 + lane];
        acc[0][j] = __builtin_amdgcn_mfma_f32_16x16x32_bf16(a0, bb, acc[0][j], 0, 0, 0);
        acc[1][j] = __builtin_amdgcn_mfma_f32_16x16x32_bf16(a1, bb, acc[1][j], 0, 0, 0);
      }
    }
    __syncthreads();  // all A-reads done before writes
    // gates L1 -> h1_t into hcat cols [64,128) (or fp32 h1f at t=14)
    float* h1f = (float*)smem;
#pragma unroll
    for (int mt = 0; mt < 2; ++mt)
#pragma unroll
      for (int r = 0; r < 4; ++r) {
        int row = 16 * mt + 4 * grp + r;
        float zi = acc[mt][0][r], zf = acc[mt][1][r];
        float zg = acc[mt][2][r], zo = acc[mt][3][r];
        float ig = sigm(zi), fg = sigm(zf), gg = tanhx(zg), og = sigm(zo);
        float c = fmaf(fg, c1r[mt * 4 + r], ig * gg);
        c1r[mt * 4 + r] = c;
        float h = og * tanhx(c);
        if (t < kT - 1) {
          hc[row * 128 + ((64 + u) ^ ((row & 7) << 3))] = f2bf(h);
        } else {
          h1f[row * 68 + u] = h;  // fp32 for FC (aliases hcat; hcat dead now)
        }
      }
    __syncthreads();
  }

  // ---------------- FC + exact-erf GELU (fp32) ----------------
  const float* h1 = (const float*)smem;
  const int o = tid & 63;
  const int ms = tid >> 6;  // rows ms*8 .. ms*8+7
  float yv[8];
  float fb = fc_b[o];
#pragma unroll
  for (int i = 0; i < 8; ++i) yv[i] = fb;
  for (int u0 = 0; u0 < 64; u0 += 4) {
    float q0 = ws[WS_FCT + (u0 + 0) * 64 + o];
    float q1 = ws[WS_FCT + (u0 + 1) * 64 + o];
    float q2 = ws[WS_FCT + (u0 + 2) * 64 + o];
    float q3 = ws[WS_FCT + (u0 + 3) * 64 + o];
#pragma unroll
    for (int i = 0; i < 8; ++i) {
      const float4 hq = *(const float4*)&h1[(ms * 8 + i) * 68 + u0];
      yv[i] = fmaf(hq.x, q0, yv[i]);
      yv[i] = fmaf(hq.y, q1, yv[i]);
      yv[i] = fmaf(hq.z, q2, yv[i]);
      yv[i] = fmaf(hq.w, q3, yv[i]);
    }
  }
#pragma unroll
  for (int i = 0; i < 8; ++i) {
    float v = yv[i];
    float g = 0.5f * v * (1.f + erff(v * 0.70710678118654752f));
    out[(size_t)(bm0 + ms * 8 + i) * 64 + o] = g;
  }
}

extern "C" void kernel_launch(void* const* d_in, const int* in_sizes, int n_in,
                              void* d_out, int out_size, void* d_ws, size_t ws_size,
                              hipStream_t stream) {
  const float* x = (const float*)d_in[0];
  const float* bn_gamma = (const float*)d_in[1];
  const float* bn_beta = (const float*)d_in[2];
  const float* w_ih0 = (const float*)d_in[3];
  const float* w_hh0 = (const float*)d_in[4];
  const float* b_ih0 = (const float*)d_in[5];
  const float* b_hh0 = (const float*)d_in[6];
  const float* w_ih1 = (const float*)d_in[7];
  const float* w_hh1 = (const float*)d_in[8];
  const float* b_ih1 = (const float*)d_in[9];
  const float* b_hh1 = (const float*)d_in[10];
  const float* fc_w = (const float*)d_in[11];
  const float* fc_b = (const float*)d_in[12];
  float* ws = (float*)d_ws;
  float* out = (float*)d_out;

  hipLaunchKernelGGL(prep_kernel, dim3(64), dim3(256), 0, stream,
                     w_hh0, w_ih1, w_hh1, b_ih0, b_hh0, b_ih1, b_hh1, fc_w, ws);
  hipLaunchKernelGGL(bn_sums_kernel, dim3(512), dim3(256), 0, stream, x, ws);
  hipLaunchKernelGGL(bn_final_kernel, dim3(1), dim3(64), 0, stream,
                     bn_gamma, bn_beta, ws);
  hipLaunchKernelGGL(lstm_fused_kernel, dim3(kB / 32), dim3(256), 0, stream,
                     x, w_ih0, fc_b, ws, out);
}

// Round 3
// 1395.873 us; speedup vs baseline: 3.6622x; 2.5139x over previous
//
#include <hip/hip_runtime.h>
#include <math.h>

// BN(ch=T) -> LSTM(1->64) -> LSTM(64->64) -> FC+GELU.  B=262144 T=15 H=64.
// v3: B-fragments hoisted to registers (loaded once per block, reused all 15 t)
//     -> kills the 11.8 GB/dispatch weight re-stream that bound v2.
//
// ws float offsets:
//   WS_SS    0     scale[15]@+0, shift[15]@+16
//   WS_B0    32    b_ih0+b_hh0 [256]
//   WS_B1    288   b_ih1+b_hh1 [256]
//   WS_FCT   1024  fcT[u][o] fp32 [64][64]
//   WS_STATS 5200  bn sums[15]@+0, sqsums[15]@+16
//   WS_BF    8192  bf16 B-fragments: 96 chunks x 64 lanes x 8 ushort (96 KB)
//     chunk<32:  L0 (w_hh0^T):  ks=chunk>>4 (K=64: 2), nt=chunk&15
//     chunk>=32: L1 ([w_ih1;w_hh1]^T): ks=(chunk-32)>>4 (K=128: 4), nt=&15
//     elem(lane,j) = B[k=32*ks+8*(lane>>4)+j][n=16*nt+(lane&15)]

typedef __attribute__((ext_vector_type(8))) short short8;
typedef __attribute__((ext_vector_type(4))) float f32x4;

namespace {
constexpr int kB = 262144;
constexpr int kT = 15;
constexpr int WS_SS = 0;
constexpr int WS_B0 = 32;
constexpr int WS_B1 = 288;
constexpr int WS_FCT = 1024;
constexpr int WS_STATS = 5200;
constexpr int WS_BF = 8192;
}  // namespace

__device__ __forceinline__ float sigm(float x) {
  return __builtin_amdgcn_rcpf(1.f + __expf(-x));
}
__device__ __forceinline__ float tanhx(float x) {
  return 1.f - 2.f * __builtin_amdgcn_rcpf(1.f + __expf(2.f * x));
}
__device__ __forceinline__ ushort f2bf(float f) {
  unsigned u = __float_as_uint(f);
  unsigned r = (u + 0x7fffu + ((u >> 16) & 1u)) >> 16;  // RNE
  return (ushort)r;
}

__global__ void prep_kernel(const float* __restrict__ w_hh0,
                            const float* __restrict__ w_ih1,
                            const float* __restrict__ w_hh1,
                            const float* __restrict__ b_ih0,
                            const float* __restrict__ b_hh0,
                            const float* __restrict__ b_ih1,
                            const float* __restrict__ b_hh1,
                            const float* __restrict__ fc_w,
                            float* __restrict__ ws) {
  const int stride = gridDim.x * blockDim.x;
  const int t0 = blockIdx.x * blockDim.x + threadIdx.x;
  ushort* bf = (ushort*)(ws + WS_BF);
  for (int i = t0; i < 96 * 512; i += stride) {
    int chunk = i >> 9, lane = (i >> 3) & 63, j = i & 7;
    float v;
    if (chunk < 32) {
      int ks = chunk >> 4, nt = chunk & 15;
      int k = 32 * ks + 8 * (lane >> 4) + j;
      int n = 16 * nt + (lane & 15);
      v = w_hh0[n * 64 + k];
    } else {
      int c2 = chunk - 32;
      int ks = c2 >> 4, nt = c2 & 15;
      int k = 32 * ks + 8 * (lane >> 4) + j;
      int n = 16 * nt + (lane & 15);
      v = (k < 64) ? w_ih1[n * 64 + k] : w_hh1[n * 64 + (k - 64)];
    }
    bf[i] = f2bf(v);
  }
  for (int i = t0; i < 4096; i += stride) {
    int u = i >> 6, o = i & 63;
    ws[WS_FCT + i] = fc_w[o * 64 + u];
  }
  for (int i = t0; i < 256; i += stride) {
    ws[WS_B0 + i] = b_ih0[i] + b_hh0[i];
    ws[WS_B1 + i] = b_ih1[i] + b_hh1[i];
  }
  for (int i = t0; i < 32; i += stride) ws[WS_STATS + i] = 0.f;
}

// Each thread owns one chunk of 15 consecutive float4s (60 elems = 4 full
// mod-15 periods, chunk-aligned so t-indices are compile-time constants).
__global__ void bn_sums_kernel(const float* __restrict__ x,
                               float* __restrict__ ws) {
  __shared__ float ls[16], lq[16];
  const int tid = threadIdx.x;
  if (tid < 16) { ls[tid] = 0.f; lq[tid] = 0.f; }
  __syncthreads();
  const float4* x4 = (const float4*)x;
  const int c0 = (blockIdx.x * 256 + tid) * 15;
  float s[15], q[15];
#pragma unroll
  for (int t = 0; t < 15; ++t) { s[t] = 0.f; q[t] = 0.f; }
#pragma unroll
  for (int c = 0; c < 15; ++c) {
    float4 v = x4[c0 + c];
    s[(4 * c + 0) % 15] += v.x; q[(4 * c + 0) % 15] += v.x * v.x;
    s[(4 * c + 1) % 15] += v.y; q[(4 * c + 1) % 15] += v.y * v.y;
    s[(4 * c + 2) % 15] += v.z; q[(4 * c + 2) % 15] += v.z * v.z;
    s[(4 * c + 3) % 15] += v.w; q[(4 * c + 3) % 15] += v.w * v.w;
  }
#pragma unroll
  for (int t = 0; t < 15; ++t) {
    atomicAdd(&ls[t], s[t]);
    atomicAdd(&lq[t], q[t]);
  }
  __syncthreads();
  if (tid < 15) {
    atomicAdd(&ws[WS_STATS + tid], ls[tid]);
    atomicAdd(&ws[WS_STATS + 16 + tid], lq[tid]);
  }
}

__global__ void bn_final_kernel(const float* __restrict__ gamma,
                                const float* __restrict__ beta,
                                float* __restrict__ ws) {
  int t = threadIdx.x;
  if (t < 15) {
    const float inv = 1.f / (float)kB;
    float mean = ws[WS_STATS + t] * inv;
    float var = ws[WS_STATS + 16 + t] * inv - mean * mean;
    float sc = gamma[t] * rsqrtf(var + 1e-5f);
    ws[WS_SS + t] = sc;
    ws[WS_SS + 16 + t] = beta[t] - mean * sc;
  }
}

// smem: [0,8192) hcat ushort[32][128] XOR-swizzled; [8192,10368) xs f32[32][17]
// phase-2 alias: [0,8704) h1f float[32][68]
__global__ __launch_bounds__(256, 2) void lstm_fused_kernel(
    const float* __restrict__ x, const float* __restrict__ w_ih0,
    const float* __restrict__ fc_b, const float* __restrict__ ws,
    float* __restrict__ out) {
  __shared__ __align__(16) char smem[10368];
  ushort* hc = (ushort*)smem;
  float* xsf = (float*)(smem + 8192);

  const int tid = threadIdx.x;
  const int bm0 = blockIdx.x * 32;
  const int lane = tid & 63;
  const int wv = tid >> 6;
  const int grp = lane >> 4;
  const int l15 = lane & 15;
  const int u = wv * 16 + l15;

  for (int i = tid; i < 32 * kT; i += 256) {
    float v = x[(size_t)bm0 * kT + i];
    int m = i / 15, tt = i - m * 15;
    xsf[m * 17 + tt] = v * ws[WS_SS + tt] + ws[WS_SS + 16 + tt];
  }
  for (int i = tid; i < 2048; i += 256) ((unsigned*)hc)[i] = 0u;

  float b0g[4], b1g[4], w0g[4];
#pragma unroll
  for (int j = 0; j < 4; ++j) {
    b0g[j] = ws[WS_B0 + u + 64 * j];
    b1g[j] = ws[WS_B1 + u + 64 * j];
    w0g[j] = w_ih0[u + 64 * j];
  }
  float c0r[8], c1r[8];
#pragma unroll
  for (int i = 0; i < 8; ++i) { c0r[i] = 0.f; c1r[i] = 0.f; }

  // ---- hoist all B fragments into registers (24 x short8 = 96 VGPR) ----
  const short8* bfr = (const short8*)(ws + WS_BF);
  short8 bL0[8], bL1[16];
#pragma unroll
  for (int ks = 0; ks < 2; ++ks)
#pragma unroll
    for (int j = 0; j < 4; ++j)
      bL0[ks * 4 + j] = bfr[(ks * 16 + wv + 4 * j) * 64 + lane];
#pragma unroll
  for (int ks = 0; ks < 4; ++ks)
#pragma unroll
    for (int j = 0; j < 4; ++j)
      bL1[ks * 4 + j] = bfr[(32 + ks * 16 + wv + 4 * j) * 64 + lane];

  auto ldA = [&](int mt, int ks) -> short8 {
    int row = l15 + 16 * mt;
    int k0 = (32 * ks + 8 * grp) ^ ((row & 7) << 3);
    return *(const short8*)&hc[row * 128 + k0];
  };

  __syncthreads();

  for (int t = 0; t < kT; ++t) {
    // ---------------- layer 0 ----------------
    f32x4 acc[2][4];
#pragma unroll
    for (int mt = 0; mt < 2; ++mt)
#pragma unroll
      for (int r = 0; r < 4; ++r) {
        float xv = xsf[(16 * mt + 4 * grp + r) * 17 + t];
#pragma unroll
        for (int j = 0; j < 4; ++j) acc[mt][j][r] = fmaf(xv, w0g[j], b0g[j]);
      }
#pragma unroll
    for (int ks = 0; ks < 2; ++ks) {
      short8 a0 = ldA(0, ks);
      short8 a1 = ldA(1, ks);
#pragma unroll
      for (int j = 0; j < 4; ++j) {
        acc[0][j] = __builtin_amdgcn_mfma_f32_16x16x32_bf16(a0, bL0[ks * 4 + j], acc[0][j], 0, 0, 0);
        acc[1][j] = __builtin_amdgcn_mfma_f32_16x16x32_bf16(a1, bL0[ks * 4 + j], acc[1][j], 0, 0, 0);
      }
    }
    __syncthreads();
#pragma unroll
    for (int mt = 0; mt < 2; ++mt)
#pragma unroll
      for (int r = 0; r < 4; ++r) {
        int row = 16 * mt + 4 * grp + r;
        float zi = acc[mt][0][r], zf = acc[mt][1][r];
        float zg = acc[mt][2][r], zo = acc[mt][3][r];
        float ig = sigm(zi), fg = sigm(zf), gg = tanhx(zg), og = sigm(zo);
        float c = fmaf(fg, c0r[mt * 4 + r], ig * gg);
        c0r[mt * 4 + r] = c;
        float h = og * tanhx(c);
        hc[row * 128 + (u ^ ((row & 7) << 3))] = f2bf(h);
      }
    __syncthreads();

    // ---------------- layer 1 ----------------
#pragma unroll
    for (int mt = 0; mt < 2; ++mt)
#pragma unroll
      for (int j = 0; j < 4; ++j)
#pragma unroll
        for (int r = 0; r < 4; ++r) acc[mt][j][r] = b1g[j];
#pragma unroll
    for (int ks = 0; ks < 4; ++ks) {
      short8 a0 = ldA(0, ks);
      short8 a1 = ldA(1, ks);
#pragma unroll
      for (int j = 0; j < 4; ++j) {
        acc[0][j] = __builtin_amdgcn_mfma_f32_16x16x32_bf16(a0, bL1[ks * 4 + j], acc[0][j], 0, 0, 0);
        acc[1][j] = __builtin_amdgcn_mfma_f32_16x16x32_bf16(a1, bL1[ks * 4 + j], acc[1][j], 0, 0, 0);
      }
    }
    __syncthreads();
    float* h1f = (float*)smem;
#pragma unroll
    for (int mt = 0; mt < 2; ++mt)
#pragma unroll
      for (int r = 0; r < 4; ++r) {
        int row = 16 * mt + 4 * grp + r;
        float zi = acc[mt][0][r], zf = acc[mt][1][r];
        float zg = acc[mt][2][r], zo = acc[mt][3][r];
        float ig = sigm(zi), fg = sigm(zf), gg = tanhx(zg), og = sigm(zo);
        float c = fmaf(fg, c1r[mt * 4 + r], ig * gg);
        c1r[mt * 4 + r] = c;
        float h = og * tanhx(c);
        if (t < kT - 1) {
          hc[row * 128 + ((64 + u) ^ ((row & 7) << 3))] = f2bf(h);
        } else {
          h1f[row * 68 + u] = h;
        }
      }
    __syncthreads();
  }

  // ---------------- FC + exact-erf GELU (fp32) ----------------
  const float* h1 = (const float*)smem;
  const int o = tid & 63;
  const int ms = tid >> 6;
  float yv[8];
  float fb = fc_b[o];
#pragma unroll
  for (int i = 0; i < 8; ++i) yv[i] = fb;
  for (int u0 = 0; u0 < 64; u0 += 4) {
    float q0 = ws[WS_FCT + (u0 + 0) * 64 + o];
    float q1 = ws[WS_FCT + (u0 + 1) * 64 + o];
    float q2 = ws[WS_FCT + (u0 + 2) * 64 + o];
    float q3 = ws[WS_FCT + (u0 + 3) * 64 + o];
#pragma unroll
    for (int i = 0; i < 8; ++i) {
      const float4 hq = *(const float4*)&h1[(ms * 8 + i) * 68 + u0];
      yv[i] = fmaf(hq.x, q0, yv[i]);
      yv[i] = fmaf(hq.y, q1, yv[i]);
      yv[i] = fmaf(hq.z, q2, yv[i]);
      yv[i] = fmaf(hq.w, q3, yv[i]);
    }
  }
#pragma unroll
  for (int i = 0; i < 8; ++i) {
    float v = yv[i];
    float g = 0.5f * v * (1.f + erff(v * 0.70710678118654752f));
    out[(size_t)(bm0 + ms * 8 + i) * 64 + o] = g;
  }
}

extern "C" void kernel_launch(void* const* d_in, const int* in_sizes, int n_in,
                              void* d_out, int out_size, void* d_ws, size_t ws_size,
                              hipStream_t stream) {
  const float* x = (const float*)d_in[0];
  const float* bn_gamma = (const float*)d_in[1];
  const float* bn_beta = (const float*)d_in[2];
  const float* w_ih0 = (const float*)d_in[3];
  const float* w_hh0 = (const float*)d_in[4];
  const float* b_ih0 = (const float*)d_in[5];
  const float* b_hh0 = (const float*)d_in[6];
  const float* w_ih1 = (const float*)d_in[7];
  const float* w_hh1 = (const float*)d_in[8];
  const float* b_ih1 = (const float*)d_in[9];
  const float* b_hh1 = (const float*)d_in[10];
  const float* fc_w = (const float*)d_in[11];
  const float* fc_b = (const float*)d_in[12];
  float* ws = (float*)d_ws;
  float* out = (float*)d_out;

  hipLaunchKernelGGL(prep_kernel, dim3(64), dim3(256), 0, stream,
                     w_hh0, w_ih1, w_hh1, b_ih0, b_hh0, b_ih1, b_hh1, fc_w, ws);
  hipLaunchKernelGGL(bn_sums_kernel, dim3(256), dim3(256), 0, stream, x, ws);
  hipLaunchKernelGGL(bn_final_kernel, dim3(1), dim3(64), 0, stream,
                     bn_gamma, bn_beta, ws);
  hipLaunchKernelGGL(lstm_fused_kernel, dim3(kB / 32), dim3(256), 0, stream,
                     x, w_ih0, fc_b, ws, out);
}

// Round 4
// 1376.704 us; speedup vs baseline: 3.7132x; 1.0139x over previous
//
#include <hip/hip_runtime.h>
#include <math.h>

// BN(ch=T) -> LSTM(1->64) -> LSTM(64->64) -> FC+GELU.  B=262144 T=15 H=64.
// v4: v3 + pinned register budget (waves_per_eu(2,2) => 256 regs/wave, no
//     spill of the 24 register-resident B-fragments) + one fewer barrier/iter.
//
// ws float offsets:
//   WS_SS    0     scale[15]@+0, shift[15]@+16
//   WS_B0    32    b_ih0+b_hh0 [256]
//   WS_B1    288   b_ih1+b_hh1 [256]
//   WS_FCT   1024  fcT[u][o] fp32 [64][64]
//   WS_STATS 5200  bn sums[15]@+0, sqsums[15]@+16
//   WS_BF    8192  bf16 B-fragments: 96 chunks x 64 lanes x 8 ushort (96 KB)
//     chunk<32:  L0 (w_hh0^T):  ks=chunk>>4 (K=64: 2), nt=chunk&15
//     chunk>=32: L1 ([w_ih1;w_hh1]^T): ks=(chunk-32)>>4 (K=128: 4), nt=&15
//     elem(lane,j) = B[k=32*ks+8*(lane>>4)+j][n=16*nt+(lane&15)]

typedef __attribute__((ext_vector_type(8))) short short8;
typedef __attribute__((ext_vector_type(4))) float f32x4;

namespace {
constexpr int kB = 262144;
constexpr int kT = 15;
constexpr int WS_SS = 0;
constexpr int WS_B0 = 32;
constexpr int WS_B1 = 288;
constexpr int WS_FCT = 1024;
constexpr int WS_STATS = 5200;
constexpr int WS_BF = 8192;
}  // namespace

__device__ __forceinline__ float sigm(float x) {
  return __builtin_amdgcn_rcpf(1.f + __expf(-x));
}
__device__ __forceinline__ float tanhx(float x) {
  return 1.f - 2.f * __builtin_amdgcn_rcpf(1.f + __expf(2.f * x));
}
__device__ __forceinline__ ushort f2bf(float f) {
  unsigned u = __float_as_uint(f);
  unsigned r = (u + 0x7fffu + ((u >> 16) & 1u)) >> 16;  // RNE
  return (ushort)r;
}

__global__ void prep_kernel(const float* __restrict__ w_hh0,
                            const float* __restrict__ w_ih1,
                            const float* __restrict__ w_hh1,
                            const float* __restrict__ b_ih0,
                            const float* __restrict__ b_hh0,
                            const float* __restrict__ b_ih1,
                            const float* __restrict__ b_hh1,
                            const float* __restrict__ fc_w,
                            float* __restrict__ ws) {
  const int stride = gridDim.x * blockDim.x;
  const int t0 = blockIdx.x * blockDim.x + threadIdx.x;
  ushort* bf = (ushort*)(ws + WS_BF);
  for (int i = t0; i < 96 * 512; i += stride) {
    int chunk = i >> 9, lane = (i >> 3) & 63, j = i & 7;
    float v;
    if (chunk < 32) {
      int ks = chunk >> 4, nt = chunk & 15;
      int k = 32 * ks + 8 * (lane >> 4) + j;
      int n = 16 * nt + (lane & 15);
      v = w_hh0[n * 64 + k];
    } else {
      int c2 = chunk - 32;
      int ks = c2 >> 4, nt = c2 & 15;
      int k = 32 * ks + 8 * (lane >> 4) + j;
      int n = 16 * nt + (lane & 15);
      v = (k < 64) ? w_ih1[n * 64 + k] : w_hh1[n * 64 + (k - 64)];
    }
    bf[i] = f2bf(v);
  }
  for (int i = t0; i < 4096; i += stride) {
    int u = i >> 6, o = i & 63;
    ws[WS_FCT + i] = fc_w[o * 64 + u];
  }
  for (int i = t0; i < 256; i += stride) {
    ws[WS_B0 + i] = b_ih0[i] + b_hh0[i];
    ws[WS_B1 + i] = b_ih1[i] + b_hh1[i];
  }
  for (int i = t0; i < 32; i += stride) ws[WS_STATS + i] = 0.f;
}

// Each thread owns one chunk of 15 consecutive float4s (60 elems = 4 full
// mod-15 periods, chunk-aligned so t-indices are compile-time constants).
__global__ void bn_sums_kernel(const float* __restrict__ x,
                               float* __restrict__ ws) {
  __shared__ float ls[16], lq[16];
  const int tid = threadIdx.x;
  if (tid < 16) { ls[tid] = 0.f; lq[tid] = 0.f; }
  __syncthreads();
  const float4* x4 = (const float4*)x;
  const int c0 = (blockIdx.x * 256 + tid) * 15;
  float s[15], q[15];
#pragma unroll
  for (int t = 0; t < 15; ++t) { s[t] = 0.f; q[t] = 0.f; }
#pragma unroll
  for (int c = 0; c < 15; ++c) {
    float4 v = x4[c0 + c];
    s[(4 * c + 0) % 15] += v.x; q[(4 * c + 0) % 15] += v.x * v.x;
    s[(4 * c + 1) % 15] += v.y; q[(4 * c + 1) % 15] += v.y * v.y;
    s[(4 * c + 2) % 15] += v.z; q[(4 * c + 2) % 15] += v.z * v.z;
    s[(4 * c + 3) % 15] += v.w; q[(4 * c + 3) % 15] += v.w * v.w;
  }
#pragma unroll
  for (int t = 0; t < 15; ++t) {
    atomicAdd(&ls[t], s[t]);
    atomicAdd(&lq[t], q[t]);
  }
  __syncthreads();
  if (tid < 15) {
    atomicAdd(&ws[WS_STATS + tid], ls[tid]);
    atomicAdd(&ws[WS_STATS + 16 + tid], lq[tid]);
  }
}

__global__ void bn_final_kernel(const float* __restrict__ gamma,
                                const float* __restrict__ beta,
                                float* __restrict__ ws) {
  int t = threadIdx.x;
  if (t < 15) {
    const float inv = 1.f / (float)kB;
    float mean = ws[WS_STATS + t] * inv;
    float var = ws[WS_STATS + 16 + t] * inv - mean * mean;
    float sc = gamma[t] * rsqrtf(var + 1e-5f);
    ws[WS_SS + t] = sc;
    ws[WS_SS + 16 + t] = beta[t] - mean * sc;
  }
}

// smem: [0,8192) hcat ushort[32][128] XOR-swizzled; [8192,10368) xs f32[32][17]
// phase-2 alias: [0,8704) h1f float[32][68]
__global__ __attribute__((amdgpu_flat_work_group_size(256, 256),
                          amdgpu_waves_per_eu(2, 2))) void lstm_fused_kernel(
    const float* __restrict__ x, const float* __restrict__ w_ih0,
    const float* __restrict__ fc_b, const float* __restrict__ ws,
    float* __restrict__ out) {
  __shared__ __align__(16) char smem[10368];
  ushort* hc = (ushort*)smem;
  float* xsf = (float*)(smem + 8192);

  const int tid = threadIdx.x;
  const int bm0 = blockIdx.x * 32;
  const int lane = tid & 63;
  const int wv = tid >> 6;
  const int grp = lane >> 4;
  const int l15 = lane & 15;
  const int u = wv * 16 + l15;

  for (int i = tid; i < 32 * kT; i += 256) {
    float v = x[(size_t)bm0 * kT + i];
    int m = i / 15, tt = i - m * 15;
    xsf[m * 17 + tt] = v * ws[WS_SS + tt] + ws[WS_SS + 16 + tt];
  }
  for (int i = tid; i < 2048; i += 256) ((unsigned*)hc)[i] = 0u;

  float b0g[4], b1g[4], w0g[4];
#pragma unroll
  for (int j = 0; j < 4; ++j) {
    b0g[j] = ws[WS_B0 + u + 64 * j];
    b1g[j] = ws[WS_B1 + u + 64 * j];
    w0g[j] = w_ih0[u + 64 * j];
  }
  float c0r[8], c1r[8];
#pragma unroll
  for (int i = 0; i < 8; ++i) { c0r[i] = 0.f; c1r[i] = 0.f; }

  // ---- all B fragments register-resident (24 x short8 = 96 regs payload) ----
  const short8* bfr = (const short8*)(ws + WS_BF);
  short8 bL0[8], bL1[16];
#pragma unroll
  for (int ks = 0; ks < 2; ++ks)
#pragma unroll
    for (int j = 0; j < 4; ++j)
      bL0[ks * 4 + j] = bfr[(ks * 16 + wv + 4 * j) * 64 + lane];
#pragma unroll
  for (int ks = 0; ks < 4; ++ks)
#pragma unroll
    for (int j = 0; j < 4; ++j)
      bL1[ks * 4 + j] = bfr[(32 + ks * 16 + wv + 4 * j) * 64 + lane];

  auto ldA = [&](int mt, int ks) -> short8 {
    int row = l15 + 16 * mt;
    int k0 = (32 * ks + 8 * grp) ^ ((row & 7) << 3);
    return *(const short8*)&hc[row * 128 + k0];
  };

  __syncthreads();

  for (int t = 0; t < kT; ++t) {
    // ---------------- layer 0 ----------------
    f32x4 acc[2][4];
#pragma unroll
    for (int mt = 0; mt < 2; ++mt)
#pragma unroll
      for (int r = 0; r < 4; ++r) {
        float xv = xsf[(16 * mt + 4 * grp + r) * 17 + t];
#pragma unroll
        for (int j = 0; j < 4; ++j) acc[mt][j][r] = fmaf(xv, w0g[j], b0g[j]);
      }
#pragma unroll
    for (int ks = 0; ks < 2; ++ks) {
      short8 a0 = ldA(0, ks);
      short8 a1 = ldA(1, ks);
#pragma unroll
      for (int j = 0; j < 4; ++j) {
        acc[0][j] = __builtin_amdgcn_mfma_f32_16x16x32_bf16(a0, bL0[ks * 4 + j], acc[0][j], 0, 0, 0);
        acc[1][j] = __builtin_amdgcn_mfma_f32_16x16x32_bf16(a1, bL0[ks * 4 + j], acc[1][j], 0, 0, 0);
      }
    }
    __syncthreads();  // L0 A-reads (h0 cols) done before h0_t overwrite
#pragma unroll
    for (int mt = 0; mt < 2; ++mt)
#pragma unroll
      for (int r = 0; r < 4; ++r) {
        int row = 16 * mt + 4 * grp + r;
        float zi = acc[mt][0][r], zf = acc[mt][1][r];
        float zg = acc[mt][2][r], zo = acc[mt][3][r];
        float ig = sigm(zi), fg = sigm(zf), gg = tanhx(zg), og = sigm(zo);
        float c = fmaf(fg, c0r[mt * 4 + r], ig * gg);
        c0r[mt * 4 + r] = c;
        float h = og * tanhx(c);
        hc[row * 128 + (u ^ ((row & 7) << 3))] = f2bf(h);
      }
    __syncthreads();  // h0_t visible (also orders prev-iter h1_t writes)

    // ---------------- layer 1 ----------------
#pragma unroll
    for (int mt = 0; mt < 2; ++mt)
#pragma unroll
      for (int j = 0; j < 4; ++j)
#pragma unroll
        for (int r = 0; r < 4; ++r) acc[mt][j][r] = b1g[j];
#pragma unroll
    for (int ks = 0; ks < 4; ++ks) {
      short8 a0 = ldA(0, ks);
      short8 a1 = ldA(1, ks);
#pragma unroll
      for (int j = 0; j < 4; ++j) {
        acc[0][j] = __builtin_amdgcn_mfma_f32_16x16x32_bf16(a0, bL1[ks * 4 + j], acc[0][j], 0, 0, 0);
        acc[1][j] = __builtin_amdgcn_mfma_f32_16x16x32_bf16(a1, bL1[ks * 4 + j], acc[1][j], 0, 0, 0);
      }
    }
    __syncthreads();  // L1 A-reads done before h1_t overwrite
    float* h1f = (float*)smem;
#pragma unroll
    for (int mt = 0; mt < 2; ++mt)
#pragma unroll
      for (int r = 0; r < 4; ++r) {
        int row = 16 * mt + 4 * grp + r;
        float zi = acc[mt][0][r], zf = acc[mt][1][r];
        float zg = acc[mt][2][r], zo = acc[mt][3][r];
        float ig = sigm(zi), fg = sigm(zf), gg = tanhx(zg), og = sigm(zo);
        float c = fmaf(fg, c1r[mt * 4 + r], ig * gg);
        c1r[mt * 4 + r] = c;
        float h = og * tanhx(c);
        if (t < kT - 1) {
          hc[row * 128 + ((64 + u) ^ ((row & 7) << 3))] = f2bf(h);
        } else {
          h1f[row * 68 + u] = h;
        }
      }
    // no barrier here: next L0 MFMA reads only h0 cols (disjoint from h1
    // writes); h1_t -> next L1 read is ordered by next iter's 2nd barrier.
  }
  __syncthreads();  // h1f visible for FC

  // ---------------- FC + exact-erf GELU (fp32) ----------------
  const float* h1 = (const float*)smem;
  const int o = tid & 63;
  const int ms = tid >> 6;
  float yv[8];
  float fb = fc_b[o];
#pragma unroll
  for (int i = 0; i < 8; ++i) yv[i] = fb;
  for (int u0 = 0; u0 < 64; u0 += 4) {
    float q0 = ws[WS_FCT + (u0 + 0) * 64 + o];
    float q1 = ws[WS_FCT + (u0 + 1) * 64 + o];
    float q2 = ws[WS_FCT + (u0 + 2) * 64 + o];
    float q3 = ws[WS_FCT + (u0 + 3) * 64 + o];
#pragma unroll
    for (int i = 0; i < 8; ++i) {
      const float4 hq = *(const float4*)&h1[(ms * 8 + i) * 68 + u0];
      yv[i] = fmaf(hq.x, q0, yv[i]);
      yv[i] = fmaf(hq.y, q1, yv[i]);
      yv[i] = fmaf(hq.z, q2, yv[i]);
      yv[i] = fmaf(hq.w, q3, yv[i]);
    }
  }
#pragma unroll
  for (int i = 0; i < 8; ++i) {
    float v = yv[i];
    float g = 0.5f * v * (1.f + erff(v * 0.70710678118654752f));
    out[(size_t)(bm0 + ms * 8 + i) * 64 + o] = g;
  }
}

extern "C" void kernel_launch(void* const* d_in, const int* in_sizes, int n_in,
                              void* d_out, int out_size, void* d_ws, size_t ws_size,
                              hipStream_t stream) {
  const float* x = (const float*)d_in[0];
  const float* bn_gamma = (const float*)d_in[1];
  const float* bn_beta = (const float*)d_in[2];
  const float* w_ih0 = (const float*)d_in[3];
  const float* w_hh0 = (const float*)d_in[4];
  const float* b_ih0 = (const float*)d_in[5];
  const float* b_hh0 = (const float*)d_in[6];
  const float* w_ih1 = (const float*)d_in[7];
  const float* w_hh1 = (const float*)d_in[8];
  const float* b_ih1 = (const float*)d_in[9];
  const float* b_hh1 = (const float*)d_in[10];
  const float* fc_w = (const float*)d_in[11];
  const float* fc_b = (const float*)d_in[12];
  float* ws = (float*)d_ws;
  float* out = (float*)d_out;

  hipLaunchKernelGGL(prep_kernel, dim3(64), dim3(256), 0, stream,
                     w_hh0, w_ih1, w_hh1, b_ih0, b_hh0, b_ih1, b_hh1, fc_w, ws);
  hipLaunchKernelGGL(bn_sums_kernel, dim3(256), dim3(256), 0, stream, x, ws);
  hipLaunchKernelGGL(bn_final_kernel, dim3(1), dim3(64), 0, stream,
                     bn_gamma, bn_beta, ws);
  hipLaunchKernelGGL(lstm_fused_kernel, dim3(kB / 32), dim3(256), 0, stream,
                     x, w_ih0, fc_b, ws, out);
}